// Round 9
// baseline (84.500 us; speedup 1.0000x reference)
//
#include <hip/hip_runtime.h>

#define H_ 8
#define D_ 32
#define B_ 32
#define N_ 4096
#define C_ 256
#define EPS_ 1e-5f

// per-block partial slot: 1024 floats S + 32 floats T, padded to 1088
#define SLOT_ 1088

typedef __attribute__((ext_vector_type(8))) short bf16x8;
typedef __attribute__((ext_vector_type(4))) float f32x4;

__device__ __forceinline__ short f2bf(float f) {
    unsigned u = __builtin_bit_cast(unsigned, f);
    unsigned r = (u + 0x7FFFu + ((u >> 16) & 1u)) >> 16;
    return (short)r;
}
__device__ __forceinline__ float bf2f(short s) {
    return __builtin_bit_cast(float, ((unsigned)(unsigned short)s) << 16);
}

// physical short-index of (row, col) in ubuf: 80 B row stride + 32 B shift per
// 8-row group -> fragment reads conflict-free (verified R2: 0 conflicts).
__device__ __forceinline__ int uidx(int r, int c) {
    return r * 40 + ((r >> 3) & 3) * 16 + c;
}

// ---------------------------------------------------------------------------
// Kernel 1: per (b,h) accumulate S = U^T U (32x32) and t = colsum(U) via MFMA.
// (unchanged since R6 — measured ~16 µs)
// ---------------------------------------------------------------------------
__global__ __launch_bounds__(256, 4)
void k1_skv(const float* __restrict__ x, float* __restrict__ Pws)
{
    __shared__ short ubuf[256 * 40 + 64];

    const int tid  = threadIdx.x;
    const int bh   = blockIdx.x >> 2;
    const int q4   = blockIdx.x & 3;
    const int b    = bh >> 3;
    const int h    = bh & 7;
    const int lane = tid & 63;
    const int wave = tid >> 6;
    const int g    = lane >> 4;
    const int cL   = lane & 15;

    f32x4 acc[2][2] = {};
    f32x4 tq[2] = {};

    bf16x8 ones;
    #pragma unroll
    for (int j = 0; j < 8; ++j) ones[j] = (short)0x3F80;

    const float* xbase = x + ((size_t)b * N_ + q4 * 1024 + tid) * C_ + h * D_;

    float4 xA[8], xB[8];
    #pragma unroll
    for (int c = 0; c < 8; ++c)
        xA[c] = reinterpret_cast<const float4*>(xbase)[c];

    auto body = [&](const float4 (&xr)[8], float4 (&nx)[8], int it, bool pf) {
        if (pf) {
            const float* p = xbase + (size_t)(it + 1) * 256 * C_;
            #pragma unroll
            for (int c = 0; c < 8; ++c)
                nx[c] = reinterpret_cast<const float4*>(p)[c];
        }

        float sum = 0.f, sq = 0.f;
        #pragma unroll
        for (int c = 0; c < 8; ++c) {
            const float4 a = xr[c];
            sum += a.x + a.y + a.z + a.w;
            sq = fmaf(a.x, a.x, fmaf(a.y, a.y, fmaf(a.z, a.z, fmaf(a.w, a.w, sq))));
        }
        const float m   = sum * (1.f / 32.f);
        const float ss  = fmaxf(sq - sum * m, 0.f);
        const float inv = 1.f / (sqrtf(ss * (1.f / 31.f)) + EPS_);

        {
            const int base = tid * 40 + ((tid >> 3) & 3) * 16;
            #pragma unroll
            for (int q = 0; q < 4; ++q) {
                const float4 a0 = xr[q * 2 + 0];
                const float4 a1 = xr[q * 2 + 1];
                bf16x8 wv;
                wv[0] = f2bf((a0.x - m) * inv); wv[1] = f2bf((a0.y - m) * inv);
                wv[2] = f2bf((a0.z - m) * inv); wv[3] = f2bf((a0.w - m) * inv);
                wv[4] = f2bf((a1.x - m) * inv); wv[5] = f2bf((a1.y - m) * inv);
                wv[6] = f2bf((a1.z - m) * inv); wv[7] = f2bf((a1.w - m) * inv);
                *reinterpret_cast<bf16x8*>(&ubuf[base + q * 8]) = wv;
            }
        }
        asm volatile("s_waitcnt lgkmcnt(0)" ::: "memory");

        #pragma unroll
        for (int ks = 0; ks < 2; ++ks) {
            const int R0 = wave * 64 + ks * 32 + 8 * g;
            bf16x8 F0, F1;
            #pragma unroll
            for (int j = 0; j < 8; ++j) {
                const int base = uidx(R0 + j, cL);
                F0[j] = ubuf[base];
                F1[j] = ubuf[base + 16];
            }
            tq[0] = __builtin_amdgcn_mfma_f32_16x16x32_bf16(ones, F0, tq[0], 0, 0, 0);
            tq[1] = __builtin_amdgcn_mfma_f32_16x16x32_bf16(ones, F1, tq[1], 0, 0, 0);
            acc[0][0] = __builtin_amdgcn_mfma_f32_16x16x32_bf16(F0, F0, acc[0][0], 0, 0, 0);
            acc[0][1] = __builtin_amdgcn_mfma_f32_16x16x32_bf16(F0, F1, acc[0][1], 0, 0, 0);
            acc[1][0] = __builtin_amdgcn_mfma_f32_16x16x32_bf16(F1, F0, acc[1][0], 0, 0, 0);
            acc[1][1] = __builtin_amdgcn_mfma_f32_16x16x32_bf16(F1, F1, acc[1][1], 0, 0, 0);
        }
    };

    body(xA, xB, 0, true);
    body(xB, xA, 1, true);
    body(xA, xB, 2, true);
    body(xB, xA, 3, false);

    __syncthreads();
    float* sred = reinterpret_cast<float*>(ubuf);
    {
        float* dst = sred + wave * 1024;
        #pragma unroll
        for (int ca = 0; ca < 2; ++ca)
            #pragma unroll
            for (int cb = 0; cb < 2; ++cb)
                #pragma unroll
                for (int r = 0; r < 4; ++r)
                    dst[(ca * 16 + g * 4 + r) * D_ + cb * 16 + cL] = acc[ca][cb][r];
    }
    if (lane < 16) {
        sred[4096 + wave * 32 + cL]      = tq[0][0];
        sred[4096 + wave * 32 + 16 + cL] = tq[1][0];
    }
    __syncthreads();

    float* slot = Pws + (size_t)blockIdx.x * SLOT_;
    {
        const float4 c0 = *reinterpret_cast<const float4*>(&sred[tid * 4]);
        const float4 c1 = *reinterpret_cast<const float4*>(&sred[1024 + tid * 4]);
        const float4 c2 = *reinterpret_cast<const float4*>(&sred[2048 + tid * 4]);
        const float4 c3 = *reinterpret_cast<const float4*>(&sred[3072 + tid * 4]);
        float4 o;
        o.x = c0.x + c1.x + c2.x + c3.x;
        o.y = c0.y + c1.y + c2.y + c3.y;
        o.z = c0.z + c1.z + c2.z + c3.z;
        o.w = c0.w + c1.w + c2.w + c3.w;
        *reinterpret_cast<float4*>(slot + tid * 4) = o;
    }
    if (tid < D_)
        slot[1024 + tid] = sred[4096 + tid] + sred[4096 + 32 + tid]
                         + sred[4096 + 64 + tid] + sred[4096 + 96 + tid];
}

// ---------------------------------------------------------------------------
// Kernel 1b: reduce partial slots + fold weights/biases AND the residual
// identity (kv' = kv + I) -> pre-packed bf16 fragments, hi+lo split.
// Fragment layout (unchanged): lane l, reg j <-> kv'[d=8*(l>>4)+j][e=16*hf+(l&15)]
// stored at kv{Hi,Lo}[bh*1024 + hf*512 + l*8 + j]. Used as the A-operand of
// the transposed k2 MFMA (A and B per-lane layouts are mutual transposes).
// ---------------------------------------------------------------------------
__global__ __launch_bounds__(256, 4)
void k_red(const float* __restrict__ Pws,
           const float* __restrict__ kw, const float* __restrict__ kb,
           const float* __restrict__ vw, const float* __restrict__ vb,
           short* __restrict__ kvHi, short* __restrict__ kvLo)
{
    const int bh  = blockIdx.x;       // 0..255
    const int h   = bh & 7;
    const int tid = threadIdx.x;
    const int d   = tid >> 3;         // 0..31
    const int e0  = (tid & 7) * 4;    // 0,4,..,28

    const float* P0 = Pws + (size_t)(bh * 4 + 0) * SLOT_;
    const float* P1 = Pws + (size_t)(bh * 4 + 1) * SLOT_;
    const float* P2 = Pws + (size_t)(bh * 4 + 2) * SLOT_;
    const float* P3 = Pws + (size_t)(bh * 4 + 3) * SLOT_;
    const float invN = 1.f / (float)N_;

    const float4 s0 = *reinterpret_cast<const float4*>(P0 + d * D_ + e0);
    const float4 s1 = *reinterpret_cast<const float4*>(P1 + d * D_ + e0);
    const float4 s2 = *reinterpret_cast<const float4*>(P2 + d * D_ + e0);
    const float4 s3 = *reinterpret_cast<const float4*>(P3 + d * D_ + e0);
    float Sde[4] = { s0.x + s1.x + s2.x + s3.x, s0.y + s1.y + s2.y + s3.y,
                     s0.z + s1.z + s2.z + s3.z, s0.w + s1.w + s2.w + s3.w };

    const float Td  = P0[1024 + d] + P1[1024 + d] + P2[1024 + d] + P3[1024 + d];
    const float wkd = kw[h * D_ + d];
    const float bkd = kb[h * D_ + d];

    #pragma unroll
    for (int j = 0; j < 4; ++j) {
        const int e = e0 + j;
        const float Te  = P0[1024 + e] + P1[1024 + e] + P2[1024 + e] + P3[1024 + e];
        const float wve = vw[h * D_ + e];
        const float bve = vb[h * D_ + e];
        float v = invN * (wkd * (wve * Sde[j] + bve * Td) + bkd * wve * Te)
                + bkd * bve;
        if (d == e) v += 1.0f;                 // residual folded into kv
        const short hi = f2bf(v);
        const short lo = f2bf(v - bf2f(hi));
        const int hf  = e >> 4;
        const int l   = ((d >> 3) << 4) | (e & 15);
        const int idx = bh * 1024 + hf * 512 + l * 8 + (d & 7);
        kvHi[idx] = hi;
        kvLo[idx] = lo;
    }
}

// ---------------------------------------------------------------------------
// Kernel 2: out^T-tile = kv'^T · q^T via mfma(kv_frag, q_frag).
// Grid: 2048 blocks x 256 thr; wave owns 16 rows; lane (g,cL) owns row wr+cL:
// loads q-slices AND stores results on the SAME row, stores are dwordx4
// (D gives 4 contiguous cols per lane). NO LDS, NO barriers; 2-head
// ping-pong register pipeline (named regs, all static indexing).
// ---------------------------------------------------------------------------
__global__ __launch_bounds__(256, 4)
void k2_out(const float* __restrict__ x,
            const short* __restrict__ kvHi, const short* __restrict__ kvLo,
            float* __restrict__ out)
{
    const int tid  = threadIdx.x;
    const int lane = tid & 63;
    const int w    = tid >> 6;
    const int g    = lane >> 4;        // 0..3
    const int cL   = lane & 15;        // 0..15
    const int b    = blockIdx.x >> 6;  // 64 blocks per batch
    const int row  = blockIdx.x * 64 + w * 16 + cL;   // this lane's row

    const float* xr   = x + (size_t)row * C_;
    float*       orow = out + (size_t)row * C_;
    const size_t fb   = (size_t)(b * H_) * 1024 + lane * 8;   // + h*1024 + hf*512

    const f32x4 zero = {0.f, 0.f, 0.f, 0.f};

    bf16x8 hA0, lA0, hA1, lA1, hB0, lB0, hB1, lB1;
    float4 qA0, qA1, qB0, qB1;

#define LOADH(H, h0, l0, h1, l1, q0, q1)                                      \
    h0 = *reinterpret_cast<const bf16x8*>(kvHi + fb + (H) * 1024);            \
    l0 = *reinterpret_cast<const bf16x8*>(kvLo + fb + (H) * 1024);            \
    h1 = *reinterpret_cast<const bf16x8*>(kvHi + fb + (H) * 1024 + 512);      \
    l1 = *reinterpret_cast<const bf16x8*>(kvLo + fb + (H) * 1024 + 512);      \
    q0 = *reinterpret_cast<const float4*>(xr + (H) * 32 + 8 * g);             \
    q1 = *reinterpret_cast<const float4*>(xr + (H) * 32 + 8 * g + 4);

#define COMPUTE(H, h0, l0, h1, l1, q0, q1)                                    \
    {                                                                         \
        bf16x8 Qb;                                                            \
        Qb[0] = f2bf(q0.x); Qb[1] = f2bf(q0.y);                               \
        Qb[2] = f2bf(q0.z); Qb[3] = f2bf(q0.w);                               \
        Qb[4] = f2bf(q1.x); Qb[5] = f2bf(q1.y);                               \
        Qb[6] = f2bf(q1.z); Qb[7] = f2bf(q1.w);                               \
        f32x4 Dv;                                                             \
        Dv = __builtin_amdgcn_mfma_f32_16x16x32_bf16(l0, Qb, zero, 0, 0, 0);  \
        Dv = __builtin_amdgcn_mfma_f32_16x16x32_bf16(h0, Qb, Dv,   0, 0, 0);  \
        *reinterpret_cast<f32x4*>(orow + (H) * 32 + 4 * g) = Dv;              \
        Dv = __builtin_amdgcn_mfma_f32_16x16x32_bf16(l1, Qb, zero, 0, 0, 0);  \
        Dv = __builtin_amdgcn_mfma_f32_16x16x32_bf16(h1, Qb, Dv,   0, 0, 0);  \
        *reinterpret_cast<f32x4*>(orow + (H) * 32 + 16 + 4 * g) = Dv;         \
    }

    LOADH(0, hA0, lA0, hA1, lA1, qA0, qA1)
    LOADH(1, hB0, lB0, hB1, lB1, qB0, qB1)
    COMPUTE(0, hA0, lA0, hA1, lA1, qA0, qA1)
    LOADH(2, hA0, lA0, hA1, lA1, qA0, qA1)
    COMPUTE(1, hB0, lB0, hB1, lB1, qB0, qB1)
    LOADH(3, hB0, lB0, hB1, lB1, qB0, qB1)
    COMPUTE(2, hA0, lA0, hA1, lA1, qA0, qA1)
    LOADH(4, hA0, lA0, hA1, lA1, qA0, qA1)
    COMPUTE(3, hB0, lB0, hB1, lB1, qB0, qB1)
    LOADH(5, hB0, lB0, hB1, lB1, qB0, qB1)
    COMPUTE(4, hA0, lA0, hA1, lA1, qA0, qA1)
    LOADH(6, hA0, lA0, hA1, lA1, qA0, qA1)
    COMPUTE(5, hB0, lB0, hB1, lB1, qB0, qB1)
    LOADH(7, hB0, lB0, hB1, lB1, qB0, qB1)
    COMPUTE(6, hA0, lA0, hA1, lA1, qA0, qA1)
    COMPUTE(7, hB0, lB0, hB1, lB1, qB0, qB1)

#undef LOADH
#undef COMPUTE
}

extern "C" void kernel_launch(void* const* d_in, const int* in_sizes, int n_in,
                              void* d_out, int out_size, void* d_ws, size_t ws_size,
                              hipStream_t stream)
{
    const float* x  = (const float*)d_in[0];
    const float* kw = (const float*)d_in[1];
    const float* kb = (const float*)d_in[2];
    const float* vw = (const float*)d_in[3];
    const float* vb = (const float*)d_in[4];
    float* outp = (float*)d_out;

    float* Pws  = (float*)d_ws;                          // 1024 x 1088 floats (4.46 MB)
    short* kvHi = (short*)(Pws + (size_t)1024 * SLOT_);  // 256 x 1024 shorts (512 KB)
    short* kvLo = kvHi + (size_t)256 * 1024;             // 256 x 1024 shorts (512 KB)

    k1_skv<<<dim3(B_ * H_ * 4), dim3(256), 0, stream>>>(x, Pws);
    k_red<<<dim3(B_ * H_), dim3(256), 0, stream>>>(Pws, kw, kb, vw, vb, kvHi, kvLo);
    k2_out<<<dim3(B_ * N_ / 64), dim3(256), 0, stream>>>(x, kvHi, kvLo, outp);
}

// Round 10
// 84.277 us; speedup vs baseline: 1.0027x; 1.0027x over previous
//
#include <hip/hip_runtime.h>

#define H_ 8
#define D_ 32
#define B_ 32
#define N_ 4096
#define C_ 256
#define EPS_ 1e-5f

// per-block partial slot: 1024 floats S + 32 floats T, padded to 1088
#define SLOT_ 1088

typedef __attribute__((ext_vector_type(8))) short bf16x8;
typedef __attribute__((ext_vector_type(4))) float f32x4;

__device__ __forceinline__ short f2bf(float f) {
    unsigned u = __builtin_bit_cast(unsigned, f);
    unsigned r = (u + 0x7FFFu + ((u >> 16) & 1u)) >> 16;
    return (short)r;
}
__device__ __forceinline__ float bf2f(short s) {
    return __builtin_bit_cast(float, ((unsigned)(unsigned short)s) << 16);
}

// physical short-index of (row, col) in ubuf: 80 B row stride + 32 B shift per
// 8-row group -> fragment reads conflict-free (verified R2: 0 conflicts).
__device__ __forceinline__ int uidx(int r, int c) {
    return r * 40 + ((r >> 3) & 3) * 16 + c;
}

// ---------------------------------------------------------------------------
// Kernel 1: per (b,h) accumulate S = U^T U (32x32) and t = colsum(U) via MFMA.
// (unchanged since R6 — measured ~16 µs)
// ---------------------------------------------------------------------------
__global__ __launch_bounds__(256, 4)
void k1_skv(const float* __restrict__ x, float* __restrict__ Pws)
{
    __shared__ short ubuf[256 * 40 + 64];

    const int tid  = threadIdx.x;
    const int bh   = blockIdx.x >> 2;
    const int q4   = blockIdx.x & 3;
    const int b    = bh >> 3;
    const int h    = bh & 7;
    const int lane = tid & 63;
    const int wave = tid >> 6;
    const int g    = lane >> 4;
    const int cL   = lane & 15;

    f32x4 acc[2][2] = {};
    f32x4 tq[2] = {};

    bf16x8 ones;
    #pragma unroll
    for (int j = 0; j < 8; ++j) ones[j] = (short)0x3F80;

    const float* xbase = x + ((size_t)b * N_ + q4 * 1024 + tid) * C_ + h * D_;

    float4 xA[8], xB[8];
    #pragma unroll
    for (int c = 0; c < 8; ++c)
        xA[c] = reinterpret_cast<const float4*>(xbase)[c];

    auto body = [&](const float4 (&xr)[8], float4 (&nx)[8], int it, bool pf) {
        if (pf) {
            const float* p = xbase + (size_t)(it + 1) * 256 * C_;
            #pragma unroll
            for (int c = 0; c < 8; ++c)
                nx[c] = reinterpret_cast<const float4*>(p)[c];
        }

        float sum = 0.f, sq = 0.f;
        #pragma unroll
        for (int c = 0; c < 8; ++c) {
            const float4 a = xr[c];
            sum += a.x + a.y + a.z + a.w;
            sq = fmaf(a.x, a.x, fmaf(a.y, a.y, fmaf(a.z, a.z, fmaf(a.w, a.w, sq))));
        }
        const float m   = sum * (1.f / 32.f);
        const float ss  = fmaxf(sq - sum * m, 0.f);
        const float inv = 1.f / (sqrtf(ss * (1.f / 31.f)) + EPS_);

        {
            const int base = tid * 40 + ((tid >> 3) & 3) * 16;
            #pragma unroll
            for (int q = 0; q < 4; ++q) {
                const float4 a0 = xr[q * 2 + 0];
                const float4 a1 = xr[q * 2 + 1];
                bf16x8 wv;
                wv[0] = f2bf((a0.x - m) * inv); wv[1] = f2bf((a0.y - m) * inv);
                wv[2] = f2bf((a0.z - m) * inv); wv[3] = f2bf((a0.w - m) * inv);
                wv[4] = f2bf((a1.x - m) * inv); wv[5] = f2bf((a1.y - m) * inv);
                wv[6] = f2bf((a1.z - m) * inv); wv[7] = f2bf((a1.w - m) * inv);
                *reinterpret_cast<bf16x8*>(&ubuf[base + q * 8]) = wv;
            }
        }
        asm volatile("s_waitcnt lgkmcnt(0)" ::: "memory");

        #pragma unroll
        for (int ks = 0; ks < 2; ++ks) {
            const int R0 = wave * 64 + ks * 32 + 8 * g;
            bf16x8 F0, F1;
            #pragma unroll
            for (int j = 0; j < 8; ++j) {
                const int base = uidx(R0 + j, cL);
                F0[j] = ubuf[base];
                F1[j] = ubuf[base + 16];
            }
            tq[0] = __builtin_amdgcn_mfma_f32_16x16x32_bf16(ones, F0, tq[0], 0, 0, 0);
            tq[1] = __builtin_amdgcn_mfma_f32_16x16x32_bf16(ones, F1, tq[1], 0, 0, 0);
            acc[0][0] = __builtin_amdgcn_mfma_f32_16x16x32_bf16(F0, F0, acc[0][0], 0, 0, 0);
            acc[0][1] = __builtin_amdgcn_mfma_f32_16x16x32_bf16(F0, F1, acc[0][1], 0, 0, 0);
            acc[1][0] = __builtin_amdgcn_mfma_f32_16x16x32_bf16(F1, F0, acc[1][0], 0, 0, 0);
            acc[1][1] = __builtin_amdgcn_mfma_f32_16x16x32_bf16(F1, F1, acc[1][1], 0, 0, 0);
        }
    };

    body(xA, xB, 0, true);
    body(xB, xA, 1, true);
    body(xA, xB, 2, true);
    body(xB, xA, 3, false);

    __syncthreads();
    float* sred = reinterpret_cast<float*>(ubuf);
    {
        float* dst = sred + wave * 1024;
        #pragma unroll
        for (int ca = 0; ca < 2; ++ca)
            #pragma unroll
            for (int cb = 0; cb < 2; ++cb)
                #pragma unroll
                for (int r = 0; r < 4; ++r)
                    dst[(ca * 16 + g * 4 + r) * D_ + cb * 16 + cL] = acc[ca][cb][r];
    }
    if (lane < 16) {
        sred[4096 + wave * 32 + cL]      = tq[0][0];
        sred[4096 + wave * 32 + 16 + cL] = tq[1][0];
    }
    __syncthreads();

    float* slot = Pws + (size_t)blockIdx.x * SLOT_;
    {
        const float4 c0 = *reinterpret_cast<const float4*>(&sred[tid * 4]);
        const float4 c1 = *reinterpret_cast<const float4*>(&sred[1024 + tid * 4]);
        const float4 c2 = *reinterpret_cast<const float4*>(&sred[2048 + tid * 4]);
        const float4 c3 = *reinterpret_cast<const float4*>(&sred[3072 + tid * 4]);
        float4 o;
        o.x = c0.x + c1.x + c2.x + c3.x;
        o.y = c0.y + c1.y + c2.y + c3.y;
        o.z = c0.z + c1.z + c2.z + c3.z;
        o.w = c0.w + c1.w + c2.w + c3.w;
        *reinterpret_cast<float4*>(slot + tid * 4) = o;
    }
    if (tid < D_)
        slot[1024 + tid] = sred[4096 + tid] + sred[4096 + 32 + tid]
                         + sred[4096 + 64 + tid] + sred[4096 + 96 + tid];
}

// ---------------------------------------------------------------------------
// Kernel 1b: reduce partial slots + fold weights/biases AND the residual
// identity (kv' = kv + I) -> pre-packed bf16 fragments, hi+lo split.
// Fragment layout: lane l, reg j <-> kv'[d=8*(l>>4)+j][e=16*hf+(l&15)]
// stored at kv{Hi,Lo}[bh*1024 + hf*512 + l*8 + j].  (unchanged from R9)
// ---------------------------------------------------------------------------
__global__ __launch_bounds__(256, 4)
void k_red(const float* __restrict__ Pws,
           const float* __restrict__ kw, const float* __restrict__ kb,
           const float* __restrict__ vw, const float* __restrict__ vb,
           short* __restrict__ kvHi, short* __restrict__ kvLo)
{
    const int bh  = blockIdx.x;       // 0..255
    const int h   = bh & 7;
    const int tid = threadIdx.x;
    const int d   = tid >> 3;         // 0..31
    const int e0  = (tid & 7) * 4;    // 0,4,..,28

    const float* P0 = Pws + (size_t)(bh * 4 + 0) * SLOT_;
    const float* P1 = Pws + (size_t)(bh * 4 + 1) * SLOT_;
    const float* P2 = Pws + (size_t)(bh * 4 + 2) * SLOT_;
    const float* P3 = Pws + (size_t)(bh * 4 + 3) * SLOT_;
    const float invN = 1.f / (float)N_;

    const float4 s0 = *reinterpret_cast<const float4*>(P0 + d * D_ + e0);
    const float4 s1 = *reinterpret_cast<const float4*>(P1 + d * D_ + e0);
    const float4 s2 = *reinterpret_cast<const float4*>(P2 + d * D_ + e0);
    const float4 s3 = *reinterpret_cast<const float4*>(P3 + d * D_ + e0);
    float Sde[4] = { s0.x + s1.x + s2.x + s3.x, s0.y + s1.y + s2.y + s3.y,
                     s0.z + s1.z + s2.z + s3.z, s0.w + s1.w + s2.w + s3.w };

    const float Td  = P0[1024 + d] + P1[1024 + d] + P2[1024 + d] + P3[1024 + d];
    const float wkd = kw[h * D_ + d];
    const float bkd = kb[h * D_ + d];

    #pragma unroll
    for (int j = 0; j < 4; ++j) {
        const int e = e0 + j;
        const float Te  = P0[1024 + e] + P1[1024 + e] + P2[1024 + e] + P3[1024 + e];
        const float wve = vw[h * D_ + e];
        const float bve = vb[h * D_ + e];
        float v = invN * (wkd * (wve * Sde[j] + bve * Td) + bkd * wve * Te)
                + bkd * bve;
        if (d == e) v += 1.0f;                 // residual folded into kv
        const short hi = f2bf(v);
        const short lo = f2bf(v - bf2f(hi));
        const int hf  = e >> 4;
        const int l   = ((d >> 3) << 4) | (e & 15);
        const int idx = bh * 1024 + hf * 512 + l * 8 + (d & 7);
        kvHi[idx] = hi;
        kvLo[idx] = lo;
    }
}

// ---------------------------------------------------------------------------
// Kernel 2: out^T-tile = kv'^T · q^T via mfma(kv_frag, q_frag)  [R9 math],
// rebuilt in the k1 mold: block = 128 rows (1024 blocks, ~3/CU), kv hi+lo
// fragments for all 8 heads in 32 KB LDS (filled once, ONE barrier,
// conflict-free stride-16B ds_read_b128). Each wave owns 32 rows = 4
// half-tiles (16 rows x 4 heads); x-fragment loads run a 3-buffer rotation
// with 24 dwordx4 in flight (~2 half-tiles of compute cover).
// ---------------------------------------------------------------------------
__global__ __launch_bounds__(256, 3)
void k2_out(const float* __restrict__ x,
            const short* __restrict__ kvHi, const short* __restrict__ kvLo,
            float* __restrict__ out)
{
    __shared__ short kvL[16384];       // 32 KB: hi frags [0,8192), lo [8192,16384)

    const int tid  = threadIdx.x;
    const int lane = tid & 63;
    const int w    = tid >> 6;
    const int g    = lane >> 4;        // 0..3
    const int cL   = lane & 15;        // 0..15
    const int row0 = blockIdx.x * 128; // flat row over B*N
    const int b    = blockIdx.x >> 5;  // 32 blocks per batch
    const int rowL = row0 + w * 16 + cL;   // lane's row for t=0 (t=1: +64)

    // ---- fill kv fragment LDS (same layout as global), one barrier
    {
        const short* srcH = kvHi + (size_t)b * 8192;
        const short* srcL = kvLo + (size_t)b * 8192;
        #pragma unroll
        for (int i = 0; i < 4; ++i) {
            const int o = (tid + i * 256) * 8;   // short index, 16 B granules
            *reinterpret_cast<bf16x8*>(&kvL[o]) =
                *reinterpret_cast<const bf16x8*>(srcH + o);
            *reinterpret_cast<bf16x8*>(&kvL[8192 + o]) =
                *reinterpret_cast<const bf16x8*>(srcL + o);
        }
    }
    __syncthreads();

    const f32x4 zero = {0.f, 0.f, 0.f, 0.f};

    float4 qA[8], qB[8], qC[8];

    // half-tile HT (0..3): rows rowL + (HT>>1)*64, heads (HT&1)*4 .. +4
#define LOADQ(HT, Q)                                                          \
    {                                                                         \
        const float* xp = x + (size_t)(rowL + ((HT) >> 1) * 64) * C_          \
                            + ((HT) & 1) * 128 + 8 * g;                       \
        _Pragma("unroll")                                                     \
        for (int j = 0; j < 4; ++j) {                                         \
            Q[2 * j]     = *reinterpret_cast<const float4*>(xp + j * 32);     \
            Q[2 * j + 1] = *reinterpret_cast<const float4*>(xp + j * 32 + 4); \
        }                                                                     \
    }

#define COMPUTE(HT, Q)                                                        \
    {                                                                         \
        float* orow = out + (size_t)(rowL + ((HT) >> 1) * 64) * C_;           \
        _Pragma("unroll")                                                     \
        for (int j = 0; j < 4; ++j) {                                         \
            const int h = ((HT) & 1) * 4 + j;                                 \
            bf16x8 Qb;                                                        \
            Qb[0] = f2bf(Q[2 * j].x);     Qb[1] = f2bf(Q[2 * j].y);           \
            Qb[2] = f2bf(Q[2 * j].z);     Qb[3] = f2bf(Q[2 * j].w);           \
            Qb[4] = f2bf(Q[2 * j + 1].x); Qb[5] = f2bf(Q[2 * j + 1].y);       \
            Qb[6] = f2bf(Q[2 * j + 1].z); Qb[7] = f2bf(Q[2 * j + 1].w);       \
            _Pragma("unroll")                                                 \
            for (int hf = 0; hf < 2; ++hf) {                                  \
                const int si = h * 1024 + hf * 512 + lane * 8;                \
                const bf16x8 hi = *reinterpret_cast<const bf16x8*>(&kvL[si]); \
                const bf16x8 lo =                                             \
                    *reinterpret_cast<const bf16x8*>(&kvL[8192 + si]);        \
                f32x4 Dv;                                                     \
                Dv = __builtin_amdgcn_mfma_f32_16x16x32_bf16(lo, Qb, zero, 0, 0, 0); \
                Dv = __builtin_amdgcn_mfma_f32_16x16x32_bf16(hi, Qb, Dv,   0, 0, 0); \
                *reinterpret_cast<f32x4*>(orow + h * 32 + hf * 16 + 4 * g) = Dv;     \
            }                                                                 \
        }                                                                     \
    }

    LOADQ(0, qA)
    LOADQ(1, qB)
    LOADQ(2, qC)
    COMPUTE(0, qA)
    LOADQ(3, qA)
    COMPUTE(1, qB)
    COMPUTE(2, qC)
    COMPUTE(3, qA)

#undef LOADQ
#undef COMPUTE
}

extern "C" void kernel_launch(void* const* d_in, const int* in_sizes, int n_in,
                              void* d_out, int out_size, void* d_ws, size_t ws_size,
                              hipStream_t stream)
{
    const float* x  = (const float*)d_in[0];
    const float* kw = (const float*)d_in[1];
    const float* kb = (const float*)d_in[2];
    const float* vw = (const float*)d_in[3];
    const float* vb = (const float*)d_in[4];
    float* outp = (float*)d_out;

    float* Pws  = (float*)d_ws;                          // 1024 x 1088 floats (4.46 MB)
    short* kvHi = (short*)(Pws + (size_t)1024 * SLOT_);  // 256 x 1024 shorts (512 KB)
    short* kvLo = kvHi + (size_t)256 * 1024;             // 256 x 1024 shorts (512 KB)

    k1_skv<<<dim3(B_ * H_ * 4), dim3(256), 0, stream>>>(x, Pws);
    k_red<<<dim3(B_ * H_), dim3(256), 0, stream>>>(Pws, kw, kb, vw, vb, kvHi, kvLo);
    k2_out<<<dim3(B_ * N_ / 128), dim3(256), 0, stream>>>(x, kvHi, kvLo, outp);
}